// Round 22
// baseline (43.907 us; speedup 1.0000x reference)
//
#include <hip/hip_runtime.h>

// Problem constants
#define B_   8
#define L_   128
#define S_   160
#define H_   768
#define T_   16
#define CD_  50
#define WD_  100
#define NGATE 200   // 4*CD
#define NEGV (-1e30f)
#define FMAXV 3.402823466e+38f
#define NELEM (B_ * S_ * H_)      // 983040 floats in bert_emb

typedef short  s16x8 __attribute__((ext_vector_type(8)));   // 8 bf16 in 4 VGPRs
typedef float  f32x4 __attribute__((ext_vector_type(4)));

// ---- workspace layout (bytes): packed weights + bf16 char table ----
// wpk[dir][row r][f 0..127]: f<50 -> w_ih[r][f]; f==63 -> bias[r]; 64<=f<114 -> w_hh[r][f-64]; else 0
// ctb[c][f 0..63]:           f<50 -> char_table[c][f]; f==63 -> 1.0 (bias multiplier); else 0
#define WPK_BYTES (2 * NGATE * 128 * 2)     // 102400
#define CTB_OFF   WPK_BYTES
#define CTB_BYTES (128 * 64 * 2)            // 16384
#define WS_NEED   (CTB_OFF + CTB_BYTES)

__device__ __forceinline__ unsigned short f2bf(float f) {   // f32 -> bf16 RNE
    unsigned u = __float_as_uint(f);
    u = (u + 0x7FFFu + ((u >> 16) & 1u)) >> 16;
    return (unsigned short)u;
}
__device__ __forceinline__ float sigm(float x) {
    return __fdividef(1.f, 1.f + __expf(-x));
}
__device__ __forceinline__ float tanh_fast(float x) {
    float a = fabsf(x);
    float e = __expf(-2.f * a);
    float t = __fdividef(1.f - e, 1.f + e);
    return copysignf(t, x);
}
__device__ __forceinline__ float4 fmax4(float4 a, float4 b) {
    return make_float4(fmaxf(a.x, b.x), fmaxf(a.y, b.y), fmaxf(a.z, b.z), fmaxf(a.w, b.w));
}

// ================== Kernel 0: one-time weight/char-table packing ==================
// Replaces the per-LSTM-block scattered gather (previously ~96 scalar loads + ~300 VALU
// per thread, repeated by 64 blocks per direction).
__global__ __launch_bounds__(512) void kprep(
        const float* __restrict__ w_ih_f, const float* __restrict__ w_hh_f,
        const float* __restrict__ b_f,
        const float* __restrict__ w_ih_b, const float* __restrict__ w_hh_b,
        const float* __restrict__ b_b,
        const float* __restrict__ char_table,
        unsigned short* __restrict__ wpk, unsigned short* __restrict__ ctb) {
    int gid = blockIdx.x * 512 + threadIdx.x;
    if (gid < 2 * NGATE) {
        int dir = gid / NGATE, r = gid - dir * NGATE;
        const float* wi = (dir ? w_ih_b : w_ih_f) + r * CD_;
        const float* wh = (dir ? w_hh_b : w_hh_f) + r * CD_;
        float bv = (dir ? b_b : b_f)[r];
        unsigned short* dst = wpk + (size_t)gid * 128;
#pragma unroll
        for (int f = 0; f < 128; ++f) {
            float v = 0.f;
            if (f < 64) {
                if (f < CD_) v = wi[f];
                else if (f == 63) v = bv;
            } else {
                int k = f - 64;
                if (k < CD_) v = wh[k];
            }
            dst[f] = f2bf(v);
        }
    } else if (gid < 2 * NGATE + 128) {
        int c = gid - 2 * NGATE;
        const float* row = char_table + c * CD_;
        unsigned short* dst = ctb + (size_t)c * 64;
#pragma unroll
        for (int f = 0; f < 64; ++f) {
            float v = 0.f;
            if (f < CD_) v = row[f];
            else if (f == 63) v = 1.0f;
            dst[f] = f2bf(v);
        }
    }
}

// ---------------- shared-memory overlays ----------------
struct LstmS {
    s16x8 xall[T_][128];   // x frags for every t                 32768 B
    s16x8 hbuf[2][128];    // h frags, double-buffered             4096 B
    int   slen[16], smask[16];
};
struct Word2S {            // two words per 512-thread block
    int   list[2][S_ + 8];
    int   cnt[2];
    float red[2][256];
};
#define SMEM_BYTES 37120

// ================== role A: MFMA BiLSTM (R18/R21-verified) + packed-table prologue ==================
// j' = 4*cell + gate permutation; D = W' x [x|h] (weights in A slot); lane's 4 accumulator
// regs = gates i,f,g,o of (cell = nt*4+q, seq = lane&15). Bias folded into K.
// R22: fragments come from d_ws packed tables -- one aligned 16B load each.
__device__ void lstm_body(int unit, char* smem,
        const int* __restrict__ char_ids, const int* __restrict__ char_count,
        const int* __restrict__ tok_mask,
        const unsigned short* __restrict__ wpk, const unsigned short* __restrict__ ctb,
        float* __restrict__ out) {
    LstmS& sh = *(LstmS*)smem;
    const int dir  = unit >> 6;
    const int grp  = unit & 63;        // 16 seqs: grp*16 ..
    const int tid  = threadIdx.x;      // 0..511
    const int lane = tid & 63;
    const int wv   = tid >> 6;         // 0..7

    // ---- prologue: metadata + zero h buffers ----
    if (tid < 16) {
        int n = grp * 16 + tid;
        int c = char_count[n];
        sh.slen[tid] = (c > 0) ? c : 1;
        int mb = 0;
        for (int t = 0; t < T_; ++t) mb |= (tok_mask[n * T_ + t] != 0) << t;
        sh.smask[tid] = mb;
    }
    if (tid < 256) { s16x8 z = {0,0,0,0,0,0,0,0}; ((s16x8*)sh.hbuf)[tid] = z; }

    // ---- per-lane geometry ----
    const int m   = lane & 3;          // gate index of the W' ROW this lane loads
    const int k2  = (lane >> 2) & 3;   // cell sub-idx of the W' ROW this lane loads
    const int q   = lane >> 4;
    const int sstar = lane & 15;       // seq owned in the D output (col = lane&15)

    // tiles: A = wv (cells 4wv+q < 32, always valid), B = 8+wv (only wv<5)
    const int  ntA = wv;
    const int  ntB = 8 + wv;
    const bool hasB = (wv < 5);
    const int  cellA = ntA * 4 + q;               // cell this lane UPDATES for tile A
    const int  cellB = ntB * 4 + q;               // 32..51 (valid < 50)
    const bool vB   = hasB && (cellB < CD_);
    const int  hofsA = ((cellA >> 3) * 16 + sstar) * 8 + (cellA & 7);
    const int  hofsB = ((cellB >> 3) * 16 + sstar) * 8 + (cellB & 7);

    // ---- W' fragments: ONE 16B load each from the packed table ----
    const int  cColA = ntA * 4 + k2;              // cell of the W' row this lane loads
    const int  cColB = ntB * 4 + k2;
    const bool vColB = hasB && (cColB < CD_);
    const int orowA = m * 50 + cColA;
    const int orowB = m * 50 + ((cColB < CD_) ? cColB : 0);   // clamp; guarded by vColB

    const unsigned short* wrA = wpk + (size_t)(dir * NGATE + orowA) * 128;
    const unsigned short* wrB = wpk + (size_t)(dir * NGATE + orowB) * 128;
    s16x8 bfA0 = *(const s16x8*)(wrA + 0 * 32 + q * 8);
    s16x8 bfA1 = *(const s16x8*)(wrA + 1 * 32 + q * 8);
    s16x8 bfA2 = *(const s16x8*)(wrA + 2 * 32 + q * 8);
    s16x8 bfA3 = *(const s16x8*)(wrA + 3 * 32 + q * 8);
    s16x8 bfB0, bfB1, bfB2, bfB3;
    {
        s16x8 z = {0,0,0,0,0,0,0,0};
        if (vColB) {
            bfB0 = *(const s16x8*)(wrB + 0 * 32 + q * 8);
            bfB1 = *(const s16x8*)(wrB + 1 * 32 + q * 8);
            bfB2 = *(const s16x8*)(wrB + 2 * 32 + q * 8);
            bfB3 = *(const s16x8*)(wrB + 3 * 32 + q * 8);
        } else { bfB0 = z; bfB1 = z; bfB2 = z; bfB3 = z; }
    }
    __syncthreads();   // slen ready

    // ---- prestage ALL x frags: ONE 16B load each from bf16 char table ----
    for (int idx = tid; idx < T_ * 128; idx += 512) {
        int t = idx >> 7;
        int u = idx & 127;
        int g = u >> 4, s = u & 15;
        int st = dir ? (sh.slen[s] - 1 - t) : t;
        s16x8 fr;
        if (st >= 0) {
            int cidv = char_ids[(grp * 16 + s) * T_ + st];
            fr = *(const s16x8*)(ctb + (size_t)cidv * 64 + g * 8);   // bias 1.0 baked at f=63
        } else {
            s16x8 z = {0,0,0,0,0,0,0,0};
            fr = z;
            if (g == 7) fr[7] = (short)0x3F80;   // bf16(1.0) at k=63 (bias applies on pad steps)
        }
        sh.xall[t][u] = fr;
    }

    const int laneofs = (q << 4) + (lane & 15);   // x/h frag read offset (col=seq=lane&15)
    const int sl_s = sh.slen[sstar];
    const int sm_s = sh.smask[sstar];

    // per-lane step mask in STEP order (bit t set => pool h of step t)
    int sms = 0;
#pragma unroll
    for (int t = 0; t < T_; ++t) {
        int tt = dir ? (sl_s - 1 - t) : t;
        if (tt >= 0 && ((sm_s >> tt) & 1)) sms |= 1 << t;
    }

    float cstA = 0.f, cstB = 0.f;
    float mrA = NEGV, mrB = NEGV;

    __syncthreads();   // xall + hbuf ready

    // DIRECT per-register gate update: d[0]=i, d[1]=f, d[2]=g, d[3]=o of (cell, seq=sstar)
#define GUPD(VLD, HOF, CST, MR, D) { \
    float cc = sigm((D)[1]) * (CST) + sigm((D)[0]) * tanh_fast((D)[2]); \
    float h  = sigm((D)[3]) * tanh_fast(cc); \
    if (VLD) { \
        CST = cc; \
        hw[HOF] = f2bf(h); \
        if ((sms >> t) & 1) MR = fmaxf(MR, h); \
    } }

    // x-partials for the NEXT step (no h dependence): dp = W'_x(t) . x(t)
#define XPART(D0P, D1P, XB) { \
    s16x8 a0_ = (XB)[laneofs]; \
    s16x8 a1_ = (XB)[64 + laneofs]; \
    f32x4 z0_ = {0.f, 0.f, 0.f, 0.f}; \
    D0P = __builtin_amdgcn_mfma_f32_16x16x32_bf16(bfA0, a0_, z0_, 0, 0, 0); \
    D0P = __builtin_amdgcn_mfma_f32_16x16x32_bf16(bfA1, a1_, D0P, 0, 0, 0); \
    if (hasB) { \
        f32x4 z1_ = {0.f, 0.f, 0.f, 0.f}; \
        D1P = __builtin_amdgcn_mfma_f32_16x16x32_bf16(bfB0, a0_, z1_, 0, 0, 0); \
        D1P = __builtin_amdgcn_mfma_f32_16x16x32_bf16(bfB1, a1_, D1P, 0, 0, 0); \
    } }

    __builtin_amdgcn_s_setprio(1);   // LSTM waves are the serial pole

    f32x4 d0p, d1p;
    XPART(d0p, d1p, sh.xall[0])      // step-0 x-partials computed before entering the loop

#pragma unroll 1
    for (int t = 0; t < T_; ++t) {
        const int cur = t & 1, nxt = cur ^ 1;
        unsigned short* hw = (unsigned short*)&sh.hbuf[nxt][0];

        // post-barrier critical path: h reads -> 2 MFMA -> gate update -> h write
        s16x8 a2 = sh.hbuf[cur][laneofs];
        s16x8 a3 = sh.hbuf[cur][64 + laneofs];

        {
            f32x4 d0 = __builtin_amdgcn_mfma_f32_16x16x32_bf16(bfA2, a2, d0p, 0, 0, 0);
            d0 = __builtin_amdgcn_mfma_f32_16x16x32_bf16(bfA3, a3, d0, 0, 0, 0);
            GUPD(true, hofsA, cstA, mrA, d0)
        }
        if (hasB) {                       // wave-uniform branch; whole wave enters
            f32x4 d1 = __builtin_amdgcn_mfma_f32_16x16x32_bf16(bfB2, a2, d1p, 0, 0, 0);
            d1 = __builtin_amdgcn_mfma_f32_16x16x32_bf16(bfB3, a3, d1, 0, 0, 0);
            GUPD(vB, hofsB, cstB, mrB, d1)
        }

        // pre-barrier work: x-partials of step t+1 (hides under other waves' updates)
        if (t + 1 < T_) XPART(d0p, d1p, sh.xall[t + 1])

        __syncthreads();   // h(t) visible for step t+1
    }

    __builtin_amdgcn_s_setprio(0);

    // ---- epilogue: pooled outputs (lane owns (cellA/cellB, sstar)) ----
    float* ob = out + (size_t)(grp * 16 + sstar) * 968 + 868 + dir * CD_;
    {
        float mm = mrA;
        if (dir && (sm_s >> sl_s)) mm = fmaxf(mm, 0.f);
        if (mm == NEGV) mm = 0.f;
        ob[cellA] = mm;
    }
    if (vB) {
        float mm = mrB;
        if (dir && (sm_s >> sl_s)) mm = fmaxf(mm, 0.f);
        if (mm == NEGV) mm = 0.f;
        ob[cellB] = mm;
    }
}

// ================== role B: two words per 512-thread block (verified R18) ==================
// Fixed 4-barrier schedule in BOTH paths so the two halves can never deadlock.
__device__ void word_body2(int blk, char* smem,
        const float* __restrict__ bert, const int* __restrict__ p2w,
        const int* __restrict__ word_ids, const float* __restrict__ word_table,
        float* __restrict__ out) {
    Word2S& sh = *(Word2S*)smem;
    const int tid = threadIdx.x;       // 0..511
    const int h   = tid >> 8;          // which word half
    const int lid = tid & 255;
    const int bl  = blk * 2 + h;       // word index 0..1023
    const int b   = bl >> 7;
    const int l   = bl & 127;

    if (lid == 0) sh.cnt[h] = 0;
    __syncthreads();                                   // s1
    if (lid < S_) {
        if (p2w[bl * S_ + lid]) {
            int p = atomicAdd(&sh.cnt[h], 1);   // order-independent (fmax commutative)
            sh.list[h][p] = lid;
        }
    }
    __syncthreads();                                   // s2
    const int n = sh.cnt[h];
    if (n > 0 && lid < ((8 - (n & 7)) & 7)) sh.list[h][n + lid] = sh.list[h][0];
    __syncthreads();                                   // s3

    float gmin = 0.f;
    if (n == 0) {      // never in practice; kept for strict correctness
        float mv = FMAXV;
        const float4* x4 = (const float4*)bert;
        for (int i = lid; i < NELEM / 4; i += 256) {
            float4 v = x4[i];
            mv = fminf(mv, fminf(fminf(v.x, v.y), fminf(v.z, v.w)));
        }
        sh.red[h][lid] = mv;
    }
    __syncthreads();                                   // s4
    if (n == 0) {
        float g = FMAXV;
        for (int k = 0; k < 256; ++k) g = fminf(g, sh.red[h][k]);
        gmin = g;
    }

    float* orow = out + (size_t)bl * 968;
    if (n > 0) {
        int n8 = (n + 7) & ~7;
        if (lid < 192) {
            const float4* bb = (const float4*)(bert + (size_t)b * S_ * H_) + lid;
            float4 mx = make_float4(-FMAXV, -FMAXV, -FMAXV, -FMAXV);
            const int* lst = sh.list[h];
            for (int i = 0; i < n8; i += 8) {
                float4 v0 = bb[(size_t)lst[i]     * 192];
                float4 v1 = bb[(size_t)lst[i + 1] * 192];
                float4 v2 = bb[(size_t)lst[i + 2] * 192];
                float4 v3 = bb[(size_t)lst[i + 3] * 192];
                float4 v4 = bb[(size_t)lst[i + 4] * 192];
                float4 v5 = bb[(size_t)lst[i + 5] * 192];
                float4 v6 = bb[(size_t)lst[i + 6] * 192];
                float4 v7 = bb[(size_t)lst[i + 7] * 192];
                mx = fmax4(mx, fmax4(fmax4(fmax4(v0, v1), fmax4(v2, v3)),
                                     fmax4(fmax4(v4, v5), fmax4(v6, v7))));
            }
            ((float4*)orow)[lid] = mx;
        } else {
            int j = lid - 192;
            int wid = word_ids[bl];
            orow[768 + j] = word_table[(size_t)wid * WD_ + j];
            if (j < WD_ - 64) orow[768 + 64 + j] = word_table[(size_t)wid * WD_ + 64 + j];
        }
    } else {
        if (lid < 192) {
            ((float4*)orow)[lid] = make_float4(gmin, gmin, gmin, gmin);
        } else {
            int j = lid - 192;
            int wid = word_ids[bl];
            orow[768 + j] = word_table[(size_t)wid * WD_ + j];
            if (j < WD_ - 64) orow[768 + 64 + j] = word_table[(size_t)wid * WD_ + 64 + j];
        }
    }

    if (l == 0 && lid < 192) {   // cls embedding = bert_emb[b,0,:]
        const float4* c4 = (const float4*)(bert + (size_t)b * S_ * H_);
        float4* co = (float4*)(out + (size_t)B_ * L_ * 968 + (size_t)b * H_);
        co[lid] = c4[lid];
    }
}

// ================== mega kernel: 128 LSTM blocks first, 512 word blocks backfill ==================
__global__ __launch_bounds__(512)
__attribute__((amdgpu_waves_per_eu(2, 4)))
void kmega(
        const float* __restrict__ bert, const int* __restrict__ p2w,
        const int* __restrict__ word_ids, const int* __restrict__ char_ids,
        const int* __restrict__ char_count, const int* __restrict__ tok_mask,
        const float* __restrict__ word_table,
        const unsigned short* __restrict__ wpk, const unsigned short* __restrict__ ctb,
        float* __restrict__ out) {
    __shared__ __align__(16) char smem[SMEM_BYTES];
    int bid = blockIdx.x;
    if (bid < 128) {
        lstm_body(bid, smem, char_ids, char_count, tok_mask, wpk, ctb, out);
    } else {
        word_body2(bid - 128, smem, bert, p2w, word_ids, word_table, out);
    }
}

extern "C" void kernel_launch(void* const* d_in, const int* in_sizes, int n_in,
                              void* d_out, int out_size, void* d_ws, size_t ws_size,
                              hipStream_t stream) {
    const float* bert       = (const float*)d_in[0];
    const int*   p2w        = (const int*)d_in[1];
    const int*   word_ids   = (const int*)d_in[2];
    const int*   char_ids   = (const int*)d_in[3];
    const int*   char_count = (const int*)d_in[4];
    const int*   tok_mask   = (const int*)d_in[5];
    const float* word_table = (const float*)d_in[6];
    const float* char_table = (const float*)d_in[7];
    const float* w_ih_f = (const float*)d_in[8];
    const float* w_hh_f = (const float*)d_in[9];
    const float* b_f    = (const float*)d_in[10];
    const float* w_ih_b = (const float*)d_in[11];
    const float* w_hh_b = (const float*)d_in[12];
    const float* b_b    = (const float*)d_in[13];

    float*          out = (float*)d_out;
    unsigned short* wpk = (unsigned short*)d_ws;
    unsigned short* ctb = (unsigned short*)((char*)d_ws + CTB_OFF);

    kprep<<<2, 512, 0, stream>>>(w_ih_f, w_hh_f, b_f, w_ih_b, w_hh_b, b_b, char_table, wpk, ctb);
    kmega<<<128 + 512, 512, 0, stream>>>(bert, p2w, word_ids, char_ids, char_count, tok_mask,
                                         word_table, wpk, ctb, out);
}

// Round 23
// 36.246 us; speedup vs baseline: 1.2114x; 1.2114x over previous
//
#include <hip/hip_runtime.h>

// Problem constants
#define B_   8
#define L_   128
#define S_   160
#define H_   768
#define T_   16
#define CD_  50
#define WD_  100
#define NGATE 200   // 4*CD
#define NEGV (-1e30f)
#define FMAXV 3.402823466e+38f
#define NELEM (B_ * S_ * H_)      // 983040 floats in bert_emb

typedef short  s16x8 __attribute__((ext_vector_type(8)));   // 8 bf16 in 4 VGPRs
typedef float  f32x4 __attribute__((ext_vector_type(4)));

__device__ __forceinline__ unsigned short f2bf(float f) {   // f32 -> bf16 RNE
    unsigned u = __float_as_uint(f);
    u = (u + 0x7FFFu + ((u >> 16) & 1u)) >> 16;
    return (unsigned short)u;
}
__device__ __forceinline__ float sigm(float x) {
    return __fdividef(1.f, 1.f + __expf(-x));
}
__device__ __forceinline__ float tanh_fast(float x) {
    float a = fabsf(x);
    float e = __expf(-2.f * a);
    float t = __fdividef(1.f - e, 1.f + e);
    return copysignf(t, x);
}
__device__ __forceinline__ float4 fmax4(float4 a, float4 b) {
    return make_float4(fmaxf(a.x, b.x), fmaxf(a.y, b.y), fmaxf(a.z, b.z), fmaxf(a.w, b.w));
}

// ---------------- shared-memory overlays ----------------
struct LstmS {
    s16x8 xall[T_][128];   // x frags for every t                 32768 B
    s16x8 hbuf[2][128];    // h frags, double-buffered             4096 B
    int   slen[16], smask[16];
};
struct Word2S {            // two words per 512-thread block
    int   list[2][S_ + 8];
    int   cnt[2];
    float red[2][256];
};
#define SMEM_BYTES 37120

// ================== role A: MFMA BiLSTM, SWAPPED operands -> direct gate regs ==================
// (verified R18, 36.3 us total) Weight N-order permuted: j' = 4*cell + gatetype.
// D = W' x [x|h]: weights in the A slot, x/h in the B slot; A/B fragment lane-layouts are
// symmetric for 16x16x32, so fragment DATA is unchanged. D row = j'local = 4*(lane>>4)+r
// => cell_local = lane>>4, gate = r; D col = seq = lane&15. Each lane's 4 accumulator
// regs are the 4 gates (i,f,g,o) of ONE (cell,seq). Bias folded into K.
__device__ void lstm_body(int unit, char* smem,
        const int* __restrict__ char_ids, const int* __restrict__ char_count,
        const int* __restrict__ tok_mask, const float* __restrict__ char_table,
        const float* __restrict__ w_ih_f, const float* __restrict__ w_hh_f,
        const float* __restrict__ b_f,
        const float* __restrict__ w_ih_b, const float* __restrict__ w_hh_b,
        const float* __restrict__ b_b,
        float* __restrict__ out) {
    LstmS& sh = *(LstmS*)smem;
    const int dir  = unit >> 6;
    const int grp  = unit & 63;        // 16 seqs: grp*16 ..
    const int tid  = threadIdx.x;      // 0..511
    const int lane = tid & 63;
    const int wv   = tid >> 6;         // 0..7

    // ---- prologue: metadata + zero h buffers ----
    if (tid < 16) {
        int n = grp * 16 + tid;
        int c = char_count[n];
        sh.slen[tid] = (c > 0) ? c : 1;
        int mb = 0;
        for (int t = 0; t < T_; ++t) mb |= (tok_mask[n * T_ + t] != 0) << t;
        sh.smask[tid] = mb;
    }
    if (tid < 256) { s16x8 z = {0,0,0,0,0,0,0,0}; ((s16x8*)sh.hbuf)[tid] = z; }

    // ---- per-lane geometry ----
    const int m   = lane & 3;          // gate index of the W' ROW this lane loads
    const int k2  = (lane >> 2) & 3;   // cell sub-idx of the W' ROW this lane loads
    const int q   = lane >> 4;
    const int sstar = lane & 15;       // seq owned in the D output (col = lane&15)

    const float* WI = dir ? w_ih_b : w_ih_f;
    const float* WH = dir ? w_hh_b : w_hh_f;
    const float* BV = dir ? b_b    : b_f;

    // tiles: A = wv (cells 4wv+q < 32, always valid), B = 8+wv (only wv<5)
    const int  ntA = wv;
    const int  ntB = 8 + wv;
    const bool hasB = (wv < 5);
    const int  cellA = ntA * 4 + q;               // cell this lane UPDATES for tile A
    const int  cellB = ntB * 4 + q;               // 32..51 (valid < 50)
    const bool vB   = hasB && (cellB < CD_);
    const int  hofsA = ((cellA >> 3) * 16 + sstar) * 8 + (cellA & 7);
    const int  hofsB = ((cellB >> 3) * 16 + sstar) * 8 + (cellB & 7);

    // ---- W' fragments -> 8 NAMED registers (lane holds W' row j'local = 4*k2+m = lane&15) ----
    const int  cColA = ntA * 4 + k2;              // cell of the W' row this lane loads
    const int  cColB = ntB * 4 + k2;
    const bool vColB = hasB && (cColB < CD_);
#define LDFRAG(FR, OROW, KT, VALID) { \
    s16x8 fr_ = {0,0,0,0,0,0,0,0}; \
    if (VALID) { \
        const float* wi_ = WI + (OROW) * CD_; \
        const float* wh_ = WH + (OROW) * CD_; \
        int kst_ = (KT) * 32 + q * 8; \
        _Pragma("unroll") \
        for (int e = 0; e < 8; ++e) { \
            int k = kst_ + e; \
            float v = 0.f; \
            if (k < 64) { \
                if (k < CD_) v = wi_[k]; \
                else if (k == 63) v = BV[OROW]; \
            } else { \
                int kk = k - 64; \
                if (kk < CD_) v = wh_[kk]; \
            } \
            fr_[e] = (short)f2bf(v); \
        } \
    } \
    FR = fr_; }

    const int orowA = m * 50 + cColA;
    const int orowB = m * 50 + ((cColB < CD_) ? cColB : 0);   // clamp; guarded by vColB
    s16x8 bfA0, bfA1, bfA2, bfA3, bfB0, bfB1, bfB2, bfB3;
    LDFRAG(bfA0, orowA, 0, true)
    LDFRAG(bfA1, orowA, 1, true)
    LDFRAG(bfA2, orowA, 2, true)
    LDFRAG(bfA3, orowA, 3, true)
    LDFRAG(bfB0, orowB, 0, vColB)
    LDFRAG(bfB1, orowB, 1, vColB)
    LDFRAG(bfB2, orowB, 2, vColB)
    LDFRAG(bfB3, orowB, 3, vColB)
    __syncthreads();   // slen ready

    // ---- prestage ALL x frags (16 t x 128 units); k=63 always 1.0 (bias mult) ----
    for (int idx = tid; idx < T_ * 128; idx += 512) {
        int t = idx >> 7;
        int u = idx & 127;
        int g = u >> 4, s = u & 15;
        int st = dir ? (sh.slen[s] - 1 - t) : t;
        s16x8 fr = {0,0,0,0,0,0,0,0};
        if (st >= 0) {
            int cidv = char_ids[(grp * 16 + s) * T_ + st];
            const float* row = char_table + cidv * CD_;
            int kbase = g * 8;
#pragma unroll
            for (int e = 0; e < 8; ++e) {
                int k = kbase + e;
                if (k < CD_) fr[e] = (short)f2bf(row[k]);
            }
        }
        if (g == 7) fr[7] = (short)0x3F80;     // bf16(1.0) at k=63
        sh.xall[t][u] = fr;
    }

    const int laneofs = (q << 4) + (lane & 15);   // x/h frag read offset (col=seq=lane&15)
    const int sl_s = sh.slen[sstar];
    const int sm_s = sh.smask[sstar];

    // per-lane step mask in STEP order (bit t set => pool h of step t)
    int sms = 0;
#pragma unroll
    for (int t = 0; t < T_; ++t) {
        int tt = dir ? (sl_s - 1 - t) : t;
        if (tt >= 0 && ((sm_s >> tt) & 1)) sms |= 1 << t;
    }

    float cstA = 0.f, cstB = 0.f;
    float mrA = NEGV, mrB = NEGV;

    __syncthreads();   // xall + hbuf ready

    // DIRECT per-register gate update: d[0]=i, d[1]=f, d[2]=g, d[3]=o of (cell, seq=sstar)
#define GUPD(VLD, HOF, CST, MR, D) { \
    float cc = sigm((D)[1]) * (CST) + sigm((D)[0]) * tanh_fast((D)[2]); \
    float h  = sigm((D)[3]) * tanh_fast(cc); \
    if (VLD) { \
        CST = cc; \
        hw[HOF] = f2bf(h); \
        if ((sms >> t) & 1) MR = fmaxf(MR, h); \
    } }

    __builtin_amdgcn_s_setprio(1);   // LSTM waves are the serial pole

#pragma unroll 1
    for (int t = 0; t < T_; ++t) {
        const int cur = t & 1, nxt = cur ^ 1;
        unsigned short* hw = (unsigned short*)&sh.hbuf[nxt][0];
        const s16x8* xb = sh.xall[t];
        s16x8 a0 = xb[laneofs];
        s16x8 a1 = xb[64 + laneofs];
        s16x8 a2 = sh.hbuf[cur][laneofs];
        s16x8 a3 = sh.hbuf[cur][64 + laneofs];

        {   // D = W'(tile A) x [x|h]   -- weights in A slot, x/h in B slot
            f32x4 d0 = {0.f, 0.f, 0.f, 0.f};
            d0 = __builtin_amdgcn_mfma_f32_16x16x32_bf16(bfA0, a0, d0, 0, 0, 0);
            d0 = __builtin_amdgcn_mfma_f32_16x16x32_bf16(bfA1, a1, d0, 0, 0, 0);
            d0 = __builtin_amdgcn_mfma_f32_16x16x32_bf16(bfA2, a2, d0, 0, 0, 0);
            d0 = __builtin_amdgcn_mfma_f32_16x16x32_bf16(bfA3, a3, d0, 0, 0, 0);
            GUPD(true, hofsA, cstA, mrA, d0)
        }
        if (hasB) {                       // wave-uniform branch; whole wave enters
            f32x4 d1 = {0.f, 0.f, 0.f, 0.f};
            d1 = __builtin_amdgcn_mfma_f32_16x16x32_bf16(bfB0, a0, d1, 0, 0, 0);
            d1 = __builtin_amdgcn_mfma_f32_16x16x32_bf16(bfB1, a1, d1, 0, 0, 0);
            d1 = __builtin_amdgcn_mfma_f32_16x16x32_bf16(bfB2, a2, d1, 0, 0, 0);
            d1 = __builtin_amdgcn_mfma_f32_16x16x32_bf16(bfB3, a3, d1, 0, 0, 0);
            GUPD(vB, hofsB, cstB, mrB, d1)
        }
        __syncthreads();   // h(t) visible for step t+1
    }

    __builtin_amdgcn_s_setprio(0);

    // ---- epilogue: pooled outputs (lane owns (cellA/cellB, sstar)) ----
    float* ob = out + (size_t)(grp * 16 + sstar) * 968 + 868 + dir * CD_;
    {
        float mm = mrA;
        if (dir && (sm_s >> sl_s)) mm = fmaxf(mm, 0.f);
        if (mm == NEGV) mm = 0.f;
        ob[cellA] = mm;
    }
    if (vB) {
        float mm = mrB;
        if (dir && (sm_s >> sl_s)) mm = fmaxf(mm, 0.f);
        if (mm == NEGV) mm = 0.f;
        ob[cellB] = mm;
    }
}

// ================== role B: two words per 512-thread block ==================
// Fixed 4-barrier schedule in BOTH paths so the two halves can never deadlock.
__device__ void word_body2(int blk, char* smem,
        const float* __restrict__ bert, const int* __restrict__ p2w,
        const int* __restrict__ word_ids, const float* __restrict__ word_table,
        float* __restrict__ out) {
    Word2S& sh = *(Word2S*)smem;
    const int tid = threadIdx.x;       // 0..511
    const int h   = tid >> 8;          // which word half
    const int lid = tid & 255;
    const int bl  = blk * 2 + h;       // word index 0..1023
    const int b   = bl >> 7;
    const int l   = bl & 127;

    if (lid == 0) sh.cnt[h] = 0;
    __syncthreads();                                   // s1
    if (lid < S_) {
        if (p2w[bl * S_ + lid]) {
            int p = atomicAdd(&sh.cnt[h], 1);   // order-independent (fmax commutative)
            sh.list[h][p] = lid;
        }
    }
    __syncthreads();                                   // s2
    const int n = sh.cnt[h];
    if (n > 0 && lid < ((8 - (n & 7)) & 7)) sh.list[h][n + lid] = sh.list[h][0];
    __syncthreads();                                   // s3

    float gmin = 0.f;
    if (n == 0) {      // never in practice; kept for strict correctness
        float mv = FMAXV;
        const float4* x4 = (const float4*)bert;
        for (int i = lid; i < NELEM / 4; i += 256) {
            float4 v = x4[i];
            mv = fminf(mv, fminf(fminf(v.x, v.y), fminf(v.z, v.w)));
        }
        sh.red[h][lid] = mv;
    }
    __syncthreads();                                   // s4
    if (n == 0) {
        float g = FMAXV;
        for (int k = 0; k < 256; ++k) g = fminf(g, sh.red[h][k]);
        gmin = g;
    }

    float* orow = out + (size_t)bl * 968;
    if (n > 0) {
        int n8 = (n + 7) & ~7;
        if (lid < 192) {
            const float4* bb = (const float4*)(bert + (size_t)b * S_ * H_) + lid;
            float4 mx = make_float4(-FMAXV, -FMAXV, -FMAXV, -FMAXV);
            const int* lst = sh.list[h];
            for (int i = 0; i < n8; i += 8) {
                float4 v0 = bb[(size_t)lst[i]     * 192];
                float4 v1 = bb[(size_t)lst[i + 1] * 192];
                float4 v2 = bb[(size_t)lst[i + 2] * 192];
                float4 v3 = bb[(size_t)lst[i + 3] * 192];
                float4 v4 = bb[(size_t)lst[i + 4] * 192];
                float4 v5 = bb[(size_t)lst[i + 5] * 192];
                float4 v6 = bb[(size_t)lst[i + 6] * 192];
                float4 v7 = bb[(size_t)lst[i + 7] * 192];
                mx = fmax4(mx, fmax4(fmax4(fmax4(v0, v1), fmax4(v2, v3)),
                                     fmax4(fmax4(v4, v5), fmax4(v6, v7))));
            }
            ((float4*)orow)[lid] = mx;
        } else {
            int j = lid - 192;
            int wid = word_ids[bl];
            orow[768 + j] = word_table[(size_t)wid * WD_ + j];
            if (j < WD_ - 64) orow[768 + 64 + j] = word_table[(size_t)wid * WD_ + 64 + j];
        }
    } else {
        if (lid < 192) {
            ((float4*)orow)[lid] = make_float4(gmin, gmin, gmin, gmin);
        } else {
            int j = lid - 192;
            int wid = word_ids[bl];
            orow[768 + j] = word_table[(size_t)wid * WD_ + j];
            if (j < WD_ - 64) orow[768 + 64 + j] = word_table[(size_t)wid * WD_ + 64 + j];
        }
    }

    if (l == 0 && lid < 192) {   // cls embedding = bert_emb[b,0,:]
        const float4* c4 = (const float4*)(bert + (size_t)b * S_ * H_);
        float4* co = (float4*)(out + (size_t)B_ * L_ * 968 + (size_t)b * H_);
        co[lid] = c4[lid];
    }
}

// ================== mega kernel: 128 LSTM blocks first, 512 word blocks backfill ==================
__global__ __launch_bounds__(512)
__attribute__((amdgpu_waves_per_eu(2, 4)))
void kmega(
        const float* __restrict__ bert, const int* __restrict__ p2w,
        const int* __restrict__ word_ids, const int* __restrict__ char_ids,
        const int* __restrict__ char_count, const int* __restrict__ tok_mask,
        const float* __restrict__ word_table, const float* __restrict__ char_table,
        const float* __restrict__ w_ih_f, const float* __restrict__ w_hh_f,
        const float* __restrict__ b_f,
        const float* __restrict__ w_ih_b, const float* __restrict__ w_hh_b,
        const float* __restrict__ b_b,
        float* __restrict__ out) {
    __shared__ __align__(16) char smem[SMEM_BYTES];
    int bid = blockIdx.x;
    if (bid < 128) {
        lstm_body(bid, smem, char_ids, char_count, tok_mask, char_table,
                  w_ih_f, w_hh_f, b_f, w_ih_b, w_hh_b, b_b, out);
    } else {
        word_body2(bid - 128, smem, bert, p2w, word_ids, word_table, out);
    }
}

extern "C" void kernel_launch(void* const* d_in, const int* in_sizes, int n_in,
                              void* d_out, int out_size, void* d_ws, size_t ws_size,
                              hipStream_t stream) {
    const float* bert       = (const float*)d_in[0];
    const int*   p2w        = (const int*)d_in[1];
    const int*   word_ids   = (const int*)d_in[2];
    const int*   char_ids   = (const int*)d_in[3];
    const int*   char_count = (const int*)d_in[4];
    const int*   tok_mask   = (const int*)d_in[5];
    const float* word_table = (const float*)d_in[6];
    const float* char_table = (const float*)d_in[7];
    const float* w_ih_f = (const float*)d_in[8];
    const float* w_hh_f = (const float*)d_in[9];
    const float* b_f    = (const float*)d_in[10];
    const float* w_ih_b = (const float*)d_in[11];
    const float* w_hh_b = (const float*)d_in[12];
    const float* b_b    = (const float*)d_in[13];

    float* out = (float*)d_out;

    kmega<<<128 + 512, 512, 0, stream>>>(bert, p2w, word_ids, char_ids, char_count, tok_mask,
                                         word_table, char_table,
                                         w_ih_f, w_hh_f, b_f, w_ih_b, w_hh_b, b_b, out);
}